// Round 1
// baseline (425.710 us; speedup 1.0000x reference)
//
#include <hip/hip_runtime.h>
#include <stdint.h>

// Problem constants (from reference setup_inputs)
#define B_DIM   16384
#define IN_DIM  2048
#define OUT_DIM 2048
#define BN_EPS  1e-5f

typedef __bf16 bf16x8 __attribute__((ext_vector_type(8)));
typedef float  f32x4  __attribute__((ext_vector_type(4)));
typedef unsigned short u16x8 __attribute__((ext_vector_type(8)));

// ---------- helpers ----------

__device__ __forceinline__ unsigned short f2bf_rne(float f) {
    unsigned u = __builtin_bit_cast(unsigned, f);
    return (unsigned short)((u + 0x7fffu + ((u >> 16) & 1u)) >> 16);
}

// async global->LDS, 16B per lane. LDS dst = wave-uniform base + lane*16.
__device__ __forceinline__ void gl_lds16(const __bf16* g, __bf16* l) {
    __builtin_amdgcn_global_load_lds(
        (const __attribute__((address_space(1))) unsigned int*)g,
        (__attribute__((address_space(3))) unsigned int*)l,
        16, 0, 0);
}

// ---------- kernel 1: x fp32 -> bf16 (RNE), 8 elems/thread ----------
__global__ __launch_bounds__(256) void convert_x_kernel(
        const float4* __restrict__ x, u16x8* __restrict__ xb) {
    int id = blockIdx.x * 256 + threadIdx.x;       // exact: 16384 blocks
    float4 a = x[2 * id];
    float4 b = x[2 * id + 1];
    u16x8 o;
    o[0] = f2bf_rne(a.x); o[1] = f2bf_rne(a.y);
    o[2] = f2bf_rne(a.z); o[3] = f2bf_rne(a.w);
    o[4] = f2bf_rne(b.x); o[5] = f2bf_rne(b.y);
    o[6] = f2bf_rne(b.z); o[7] = f2bf_rne(b.w);
    xb[id] = o;
}

// ---------- kernel 2: w fp32 -> sign bf16 (+1/-1); also zero stat accums ----------
__global__ __launch_bounds__(256) void convert_w_kernel(
        const float4* __restrict__ w, u16x8* __restrict__ wb,
        float4* __restrict__ stats /* colsum[2048]+colsumsq[2048] */) {
    int id = blockIdx.x * 256 + threadIdx.x;       // exact: 2048 blocks
    if (id < 1024) stats[id] = make_float4(0.f, 0.f, 0.f, 0.f);
    float4 a = w[2 * id];
    float4 b = w[2 * id + 1];
    // w >= 0 -> +1.0bf16 (0x3F80), w < 0 -> -1.0bf16 (0xBF80). (-0.0 >= 0 -> +1, matches ref)
    u16x8 o;
    o[0] = (unsigned short)((a.x < 0.f) ? 0xBF80u : 0x3F80u);
    o[1] = (unsigned short)((a.y < 0.f) ? 0xBF80u : 0x3F80u);
    o[2] = (unsigned short)((a.z < 0.f) ? 0xBF80u : 0x3F80u);
    o[3] = (unsigned short)((a.w < 0.f) ? 0xBF80u : 0x3F80u);
    o[4] = (unsigned short)((b.x < 0.f) ? 0xBF80u : 0x3F80u);
    o[5] = (unsigned short)((b.y < 0.f) ? 0xBF80u : 0x3F80u);
    o[6] = (unsigned short)((b.z < 0.f) ? 0xBF80u : 0x3F80u);
    o[7] = (unsigned short)((b.w < 0.f) ? 0xBF80u : 0x3F80u);
    wb[id] = o;
}

// ---------- kernel 3: bf16 GEMM (NT) + column sum/sumsq epilogue ----------
// A: [B_DIM, IN_DIM] bf16 row-major; Bw: [OUT_DIM, IN_DIM] bf16 row-major (= B^T input).
// Y[m][n] = sum_k A[m][k]*Bw[n][k], written fp32 to d_out.
// 128x128 tile, BK=32, 256 threads = 4 waves in 2x2, each wave 4x4 of 16x16x32 MFMA.
__global__ __launch_bounds__(256, 2) void gemm_bn_kernel(
        const __bf16* __restrict__ A, const __bf16* __restrict__ Bw,
        float* __restrict__ Y,
        float* __restrict__ colsum, float* __restrict__ colsumsq) {
    __shared__ __bf16 sA[128 * 32];   // row-major [row][k], 64B rows
    __shared__ __bf16 sB[128 * 32];

    const int tid  = threadIdx.x;
    const int wave = tid >> 6;
    const int lane = tid & 63;
    const int wm = wave >> 1;         // wave row (0..1) -> 64 rows of M
    const int wn = wave & 1;          // wave col (0..1) -> 64 cols of N
    const int lr = lane & 15;         // MFMA row/col-within-16
    const int lq = lane >> 4;         // quad 0..3

    const int bn = blockIdx.x * 128;  // N tile (16)
    const int bm = blockIdx.y * 128;  // M tile (128)

    // staging: each wave fills 2 chunks of 16 rows (16 rows x 32 k = 1024B = 64 lanes * 16B)
    const int srow = lane >> 2;             // 0..15
    const int scol = (lane & 3) * 8;        // 0,8,16,24
    const int chunk0 = wave * 2;
    const __bf16* ag0 = A  + (size_t)(bm + chunk0 * 16 + srow) * IN_DIM + scol;
    const __bf16* ag1 = ag0 + 16 * IN_DIM;
    const __bf16* bg0 = Bw + (size_t)(bn + chunk0 * 16 + srow) * IN_DIM + scol;
    const __bf16* bg1 = bg0 + 16 * IN_DIM;
    __bf16* la0 = sA + chunk0 * 512;
    __bf16* la1 = sA + (chunk0 + 1) * 512;
    __bf16* lb0 = sB + chunk0 * 512;
    __bf16* lb1 = sB + (chunk0 + 1) * 512;

    // fragment LDS offsets: lane holds row (tile16*16 + lr), k = lq*8..+7
    const int aoff = (wm * 64 + lr) * 32 + lq * 8;
    const int boff = (wn * 64 + lr) * 32 + lq * 8;

    f32x4 acc[4][4];
#pragma unroll
    for (int i = 0; i < 4; ++i)
#pragma unroll
        for (int j = 0; j < 4; ++j) {
            f32x4 z = {0.f, 0.f, 0.f, 0.f};
            acc[i][j] = z;
        }

    for (int k0 = 0; k0 < IN_DIM; k0 += 32) {
        __syncthreads();                       // previous tile's ds_reads done
        gl_lds16(ag0 + k0, la0);
        gl_lds16(ag1 + k0, la1);
        gl_lds16(bg0 + k0, lb0);
        gl_lds16(bg1 + k0, lb1);
        __syncthreads();                       // staging complete (vmcnt(0) drain)

        bf16x8 av[4], bv[4];
#pragma unroll
        for (int i = 0; i < 4; ++i)
            av[i] = *(const bf16x8*)(sA + aoff + i * 512);
#pragma unroll
        for (int j = 0; j < 4; ++j)
            bv[j] = *(const bf16x8*)(sB + boff + j * 512);
#pragma unroll
        for (int i = 0; i < 4; ++i)
#pragma unroll
            for (int j = 0; j < 4; ++j)
                acc[i][j] = __builtin_amdgcn_mfma_f32_16x16x32_bf16(
                    av[i], bv[j], acc[i][j], 0, 0, 0);
    }

    // epilogue 1: write fp32 Y (C/D layout: col = lr, row = lq*4 + r)
#pragma unroll
    for (int i = 0; i < 4; ++i) {
        int row0 = bm + wm * 64 + i * 16 + lq * 4;
#pragma unroll
        for (int r = 0; r < 4; ++r) {
            float* yrow = Y + (size_t)(row0 + r) * OUT_DIM + bn + wn * 64 + lr;
#pragma unroll
            for (int j = 0; j < 4; ++j)
                yrow[j * 16] = acc[i][j][r];
        }
    }

    // epilogue 2: per-column partial sum / sumsq -> atomics
#pragma unroll
    for (int j = 0; j < 4; ++j) {
        float s = 0.f, q = 0.f;
#pragma unroll
        for (int i = 0; i < 4; ++i)
#pragma unroll
            for (int r = 0; r < 4; ++r) {
                float v = acc[i][j][r];
                s += v;
                q += v * v;
            }
        // combine the 4 quads (same column, different rows)
        s += __shfl_xor(s, 16); s += __shfl_xor(s, 32);
        q += __shfl_xor(q, 16); q += __shfl_xor(q, 32);
        if (lq == 0) {
            int col = bn + wn * 64 + j * 16 + lr;
            atomicAdd(&colsum[col], s);
            atomicAdd(&colsumsq[col], q);
        }
    }
}

// ---------- kernel 4: finalize BN params ----------
__global__ __launch_bounds__(256) void finalize_kernel(
        const float* __restrict__ colsum, const float* __restrict__ colsumsq,
        const float* __restrict__ gamma, const float* __restrict__ beta,
        float* __restrict__ scale, float* __restrict__ bias) {
    int n = blockIdx.x * 256 + threadIdx.x;
    if (n < OUT_DIM) {
        const float inv = 1.f / (float)B_DIM;
        float mean = colsum[n] * inv;
        float var  = colsumsq[n] * inv - mean * mean;
        float sc   = gamma[n] * rsqrtf(var + BN_EPS);
        scale[n] = sc;
        bias[n]  = beta[n] - mean * sc;
    }
}

// ---------- kernel 5: in-place affine + ReLU on d_out ----------
__global__ __launch_bounds__(256) void bn_relu_kernel(
        float4* __restrict__ y, const float4* __restrict__ scale4,
        const float4* __restrict__ bias4) {
    int id = blockIdx.x * 256 + threadIdx.x;   // exact: 32768 blocks
    int c4 = id & (OUT_DIM / 4 - 1);           // column group (row-major, 2048%4==0)
    float4 v = y[id];
    float4 s = scale4[c4];
    float4 b = bias4[c4];
    v.x = fmaxf(fmaf(v.x, s.x, b.x), 0.f);
    v.y = fmaxf(fmaf(v.y, s.y, b.y), 0.f);
    v.z = fmaxf(fmaf(v.z, s.z, b.z), 0.f);
    v.w = fmaxf(fmaf(v.w, s.w, b.w), 0.f);
    y[id] = v;
}

// ---------- launch ----------
extern "C" void kernel_launch(void* const* d_in, const int* in_sizes, int n_in,
                              void* d_out, int out_size, void* d_ws, size_t ws_size,
                              hipStream_t stream) {
    const float* x     = (const float*)d_in[0];   // [16384, 2048]
    const float* w     = (const float*)d_in[1];   // [2048, 2048]
    const float* gamma = (const float*)d_in[2];   // [2048]
    const float* beta  = (const float*)d_in[3];   // [2048]
    float* out = (float*)d_out;                   // [16384, 2048]

    char* ws = (char*)d_ws;
    // ws layout (all 256B-aligned): xb 64MB | wb 8MB | colsum | colsumsq | scale | bias
    __bf16* xb = (__bf16*)ws;                                   // 67,108,864 B
    __bf16* wb = (__bf16*)(ws + 67108864);                      //  8,388,608 B
    float* colsum   = (float*)(ws + 75497472);                  // 2048 f
    float* colsumsq = colsum + 2048;
    float* scale    = colsum + 4096;
    float* bias     = colsum + 6144;

    convert_x_kernel<<<16384, 256, 0, stream>>>((const float4*)x, (u16x8*)xb);
    convert_w_kernel<<<2048, 256, 0, stream>>>((const float4*)w, (u16x8*)wb,
                                               (float4*)colsum);
    gemm_bn_kernel<<<dim3(OUT_DIM / 128, B_DIM / 128), 256, 0, stream>>>(
        xb, wb, out, colsum, colsumsq);
    finalize_kernel<<<8, 256, 0, stream>>>(colsum, colsumsq, gamma, beta, scale, bias);
    bn_relu_kernel<<<(B_DIM * OUT_DIM / 4) / 256, 256, 0, stream>>>(
        (float4*)out, (const float4*)scale, (const float4*)bias);
}

// Round 2
// 406.876 us; speedup vs baseline: 1.0463x; 1.0463x over previous
//
#include <hip/hip_runtime.h>
#include <stdint.h>

// Problem constants (from reference setup_inputs)
#define B_DIM   16384
#define IN_DIM  2048
#define OUT_DIM 2048
#define BN_EPS  1e-5f

typedef __bf16 bf16x8 __attribute__((ext_vector_type(8)));
typedef float  f32x4  __attribute__((ext_vector_type(4)));
typedef unsigned short u16x4 __attribute__((ext_vector_type(4)));
typedef unsigned short u16x8 __attribute__((ext_vector_type(8)));

// ---------- helpers ----------

__device__ __forceinline__ unsigned short f2bf_rne(float f) {
    unsigned u = __builtin_bit_cast(unsigned, f);
    return (unsigned short)((u + 0x7fffu + ((u >> 16) & 1u)) >> 16);
}
__device__ __forceinline__ float bf2f(unsigned short h) {
    unsigned u = ((unsigned)h) << 16;
    return __builtin_bit_cast(float, u);
}

// async global->LDS, 16B per lane. LDS dst = wave-uniform base + lane*16.
__device__ __forceinline__ void gl_lds16(const __bf16* g, __bf16* l) {
    __builtin_amdgcn_global_load_lds(
        (const __attribute__((address_space(1))) unsigned int*)g,
        (__attribute__((address_space(3))) unsigned int*)l,
        16, 0, 0);
}

// ---------- kernel 1: x fp32 -> bf16 (RNE). 4 elems/thread, fully coalesced ----------
__global__ __launch_bounds__(256) void convert_x_kernel(
        const float4* __restrict__ x, u16x4* __restrict__ xb) {
    int id = blockIdx.x * 256 + threadIdx.x;       // exact: 32768 blocks
    float4 a = x[id];                              // 16B coalesced read
    u16x4 o;
    o[0] = f2bf_rne(a.x); o[1] = f2bf_rne(a.y);
    o[2] = f2bf_rne(a.z); o[3] = f2bf_rne(a.w);
    xb[id] = o;                                    // 8B coalesced write
}

// ---------- kernel 2: w fp32 -> sign bf16 (+1/-1); also zero stat accums ----------
__global__ __launch_bounds__(256) void convert_w_kernel(
        const float4* __restrict__ w, u16x4* __restrict__ wb,
        float4* __restrict__ stats /* colsum[2048]+colsumsq[2048] */) {
    int id = blockIdx.x * 256 + threadIdx.x;       // exact: 4096 blocks
    if (id < 1024) stats[id] = make_float4(0.f, 0.f, 0.f, 0.f);
    float4 a = w[id];
    // w >= 0 -> +1.0bf16 (0x3F80), w < 0 -> -1.0bf16 (0xBF80). (-0.0 >= 0 -> +1, matches ref)
    u16x4 o;
    o[0] = (unsigned short)((a.x < 0.f) ? 0xBF80u : 0x3F80u);
    o[1] = (unsigned short)((a.y < 0.f) ? 0xBF80u : 0x3F80u);
    o[2] = (unsigned short)((a.z < 0.f) ? 0xBF80u : 0x3F80u);
    o[3] = (unsigned short)((a.w < 0.f) ? 0xBF80u : 0x3F80u);
    wb[id] = o;
}

// ---------- kernel 3: bf16 GEMM (NT) + column sum/sumsq epilogue ----------
// A: [B_DIM, IN_DIM] bf16 row-major; Bw: [OUT_DIM, IN_DIM] bf16 row-major.
// Y[m][n] = sum_k A[m][k]*Bw[n][k]. Template: write Y as bf16 (ws path) or fp32.
// 128x128 tile, BK=32, 256 threads = 4 waves in 2x2, each wave 4x4 of 16x16x32 MFMA.
template <bool BF16OUT>
__global__ __launch_bounds__(256, 2) void gemm_bn_kernel(
        const __bf16* __restrict__ A, const __bf16* __restrict__ Bw,
        unsigned short* __restrict__ Yb, float* __restrict__ Yf,
        float* __restrict__ colsum, float* __restrict__ colsumsq) {
    __shared__ __bf16 sA[128 * 32];   // row-major [row][k], 64B rows
    __shared__ __bf16 sB[128 * 32];

    const int tid  = threadIdx.x;
    const int wave = tid >> 6;
    const int lane = tid & 63;
    const int wm = wave >> 1;         // wave row (0..1) -> 64 rows of M
    const int wn = wave & 1;          // wave col (0..1) -> 64 cols of N
    const int lr = lane & 15;         // MFMA row/col-within-16
    const int lq = lane >> 4;         // quad 0..3

    // XCD swizzle: HW round-robins blockIdx%8 across XCDs. Remap so each XCD
    // gets a contiguous range of logical tiles (16 full bm-rows) -> same-A
    // blocks share an XCD's L2. Perf heuristic only.
    const int b    = blockIdx.x;               // 0..2047
    const int lb   = (b & 7) * 256 + (b >> 3); // bijection on [0,2048)
    const int bm   = (lb >> 4) * 128;          // 128 M tiles
    const int bn   = (lb & 15) * 128;          // 16 N tiles

    // staging: each wave fills 2 chunks of 16 rows (16 rows x 32 k = 1024B)
    const int srow = lane >> 2;             // 0..15
    const int scol = (lane & 3) * 8;        // 0,8,16,24
    const int chunk0 = wave * 2;
    const __bf16* ag0 = A  + (size_t)(bm + chunk0 * 16 + srow) * IN_DIM + scol;
    const __bf16* ag1 = ag0 + 16 * IN_DIM;
    const __bf16* bg0 = Bw + (size_t)(bn + chunk0 * 16 + srow) * IN_DIM + scol;
    const __bf16* bg1 = bg0 + 16 * IN_DIM;
    __bf16* la0 = sA + chunk0 * 512;
    __bf16* la1 = sA + (chunk0 + 1) * 512;
    __bf16* lb0 = sB + chunk0 * 512;
    __bf16* lb1 = sB + (chunk0 + 1) * 512;

    // fragment LDS offsets: lane holds row (tile16*16 + lr), k = lq*8..+7
    const int aoff = (wm * 64 + lr) * 32 + lq * 8;
    const int boff = (wn * 64 + lr) * 32 + lq * 8;

    f32x4 acc[4][4];
#pragma unroll
    for (int i = 0; i < 4; ++i)
#pragma unroll
        for (int j = 0; j < 4; ++j) {
            f32x4 z = {0.f, 0.f, 0.f, 0.f};
            acc[i][j] = z;
        }

    for (int k0 = 0; k0 < IN_DIM; k0 += 32) {
        __syncthreads();                       // previous tile's ds_reads done
        gl_lds16(ag0 + k0, la0);
        gl_lds16(ag1 + k0, la1);
        gl_lds16(bg0 + k0, lb0);
        gl_lds16(bg1 + k0, lb1);
        __syncthreads();                       // staging complete

        bf16x8 av[4], bv[4];
#pragma unroll
        for (int i = 0; i < 4; ++i)
            av[i] = *(const bf16x8*)(sA + aoff + i * 512);
#pragma unroll
        for (int j = 0; j < 4; ++j)
            bv[j] = *(const bf16x8*)(sB + boff + j * 512);
#pragma unroll
        for (int i = 0; i < 4; ++i)
#pragma unroll
            for (int j = 0; j < 4; ++j)
                acc[i][j] = __builtin_amdgcn_mfma_f32_16x16x32_bf16(
                    av[i], bv[j], acc[i][j], 0, 0, 0);
    }

    // epilogue 1: write Y (C/D layout: col = lr, row = lq*4 + r)
#pragma unroll
    for (int i = 0; i < 4; ++i) {
        int row0 = bm + wm * 64 + i * 16 + lq * 4;
#pragma unroll
        for (int r = 0; r < 4; ++r) {
            size_t base = (size_t)(row0 + r) * OUT_DIM + bn + wn * 64 + lr;
            if (BF16OUT) {
#pragma unroll
                for (int j = 0; j < 4; ++j)
                    Yb[base + j * 16] = f2bf_rne(acc[i][j][r]);
            } else {
#pragma unroll
                for (int j = 0; j < 4; ++j)
                    Yf[base + j * 16] = acc[i][j][r];
            }
        }
    }

    // epilogue 2: per-column partial sum / sumsq (exact fp32 accs) -> atomics
#pragma unroll
    for (int j = 0; j < 4; ++j) {
        float s = 0.f, q = 0.f;
#pragma unroll
        for (int i = 0; i < 4; ++i)
#pragma unroll
            for (int r = 0; r < 4; ++r) {
                float v = acc[i][j][r];
                s += v;
                q += v * v;
            }
        s += __shfl_xor(s, 16); s += __shfl_xor(s, 32);
        q += __shfl_xor(q, 16); q += __shfl_xor(q, 32);
        if (lq == 0) {
            int col = bn + wn * 64 + j * 16 + lr;
            atomicAdd(&colsum[col], s);
            atomicAdd(&colsumsq[col], q);
        }
    }
}

// ---------- kernel 4: finalize BN params ----------
__global__ __launch_bounds__(256) void finalize_kernel(
        const float* __restrict__ colsum, const float* __restrict__ colsumsq,
        const float* __restrict__ gamma, const float* __restrict__ beta,
        float* __restrict__ scale, float* __restrict__ bias) {
    int n = blockIdx.x * 256 + threadIdx.x;
    if (n < OUT_DIM) {
        const float inv = 1.f / (float)B_DIM;
        float mean = colsum[n] * inv;
        float var  = colsumsq[n] * inv - mean * mean;
        float sc   = gamma[n] * rsqrtf(var + BN_EPS);
        scale[n] = sc;
        bias[n]  = beta[n] - mean * sc;
    }
}

// ---------- kernel 5a: bf16 Y -> affine+ReLU -> fp32 out. 4 elems/thread ----------
__global__ __launch_bounds__(256) void bn_relu_bf16_kernel(
        const u16x4* __restrict__ yb, float4* __restrict__ out,
        const float4* __restrict__ scale4, const float4* __restrict__ bias4) {
    int id = blockIdx.x * 256 + threadIdx.x;   // exact: 32768 blocks
    int c4 = id & (OUT_DIM / 4 - 1);           // column group (2048%4==0)
    u16x4 h = yb[id];                          // 8B coalesced read
    float4 s = scale4[c4];
    float4 b = bias4[c4];
    float4 v;
    v.x = fmaxf(fmaf(bf2f(h[0]), s.x, b.x), 0.f);
    v.y = fmaxf(fmaf(bf2f(h[1]), s.y, b.y), 0.f);
    v.z = fmaxf(fmaf(bf2f(h[2]), s.z, b.z), 0.f);
    v.w = fmaxf(fmaf(bf2f(h[3]), s.w, b.w), 0.f);
    out[id] = v;                               // 16B coalesced write
}

// ---------- kernel 5b: fp32 in-place fallback ----------
__global__ __launch_bounds__(256) void bn_relu_f32_kernel(
        float4* __restrict__ y, const float4* __restrict__ scale4,
        const float4* __restrict__ bias4) {
    int id = blockIdx.x * 256 + threadIdx.x;
    int c4 = id & (OUT_DIM / 4 - 1);
    float4 v = y[id];
    float4 s = scale4[c4];
    float4 b = bias4[c4];
    v.x = fmaxf(fmaf(v.x, s.x, b.x), 0.f);
    v.y = fmaxf(fmaf(v.y, s.y, b.y), 0.f);
    v.z = fmaxf(fmaf(v.z, s.z, b.z), 0.f);
    v.w = fmaxf(fmaf(v.w, s.w, b.w), 0.f);
    y[id] = v;
}

// ---------- launch ----------
extern "C" void kernel_launch(void* const* d_in, const int* in_sizes, int n_in,
                              void* d_out, int out_size, void* d_ws, size_t ws_size,
                              hipStream_t stream) {
    const float* x     = (const float*)d_in[0];   // [16384, 2048]
    const float* w     = (const float*)d_in[1];   // [2048, 2048]
    const float* gamma = (const float*)d_in[2];   // [2048]
    const float* beta  = (const float*)d_in[3];   // [2048]
    float* out = (float*)d_out;                   // [16384, 2048]

    char* ws = (char*)d_ws;
    // ws layout: xb 64MB | wb 8MB | yb 64MB | colsum | colsumsq | scale | bias
    const size_t XB_OFF = 0;
    const size_t WB_OFF = 67108864;
    const size_t YB_OFF = WB_OFF + 8388608;                 // 75,497,472
    const size_t ST_OFF = YB_OFF + 67108864;                // 142,606,336
    const size_t NEED   = ST_OFF + 8192 * 4;                // + stats

    __bf16* xb = (__bf16*)(ws + XB_OFF);
    __bf16* wb = (__bf16*)(ws + WB_OFF);
    unsigned short* yb = (unsigned short*)(ws + YB_OFF);
    bool use_bf16y = ws_size >= NEED;
    float* colsum = use_bf16y ? (float*)(ws + ST_OFF) : (float*)(ws + YB_OFF);
    float* colsumsq = colsum + 2048;
    float* scale    = colsum + 4096;
    float* bias     = colsum + 6144;

    convert_x_kernel<<<32768, 256, 0, stream>>>((const float4*)x, (u16x4*)xb);
    convert_w_kernel<<<4096, 256, 0, stream>>>((const float4*)w, (u16x4*)wb,
                                               (float4*)colsum);
    if (use_bf16y) {
        gemm_bn_kernel<true><<<2048, 256, 0, stream>>>(
            xb, wb, yb, out, colsum, colsumsq);
        finalize_kernel<<<8, 256, 0, stream>>>(colsum, colsumsq, gamma, beta,
                                               scale, bias);
        bn_relu_bf16_kernel<<<32768, 256, 0, stream>>>(
            (const u16x4*)yb, (float4*)out, (const float4*)scale,
            (const float4*)bias);
    } else {
        gemm_bn_kernel<false><<<2048, 256, 0, stream>>>(
            xb, wb, yb, out, colsum, colsumsq);
        finalize_kernel<<<8, 256, 0, stream>>>(colsum, colsumsq, gamma, beta,
                                               scale, bias);
        bn_relu_f32_kernel<<<32768, 256, 0, stream>>>(
            (float4*)out, (const float4*)scale, (const float4*)bias);
    }
}

// Round 3
// 342.641 us; speedup vs baseline: 1.2424x; 1.1875x over previous
//
#include <hip/hip_runtime.h>
#include <stdint.h>

// Problem constants (from reference setup_inputs)
#define B_DIM   16384
#define IN_DIM  2048
#define OUT_DIM 2048
#define BN_EPS  1e-5f

typedef int    i32x4 __attribute__((ext_vector_type(4)));
typedef unsigned short u16x4 __attribute__((ext_vector_type(4)));

// ---------- helpers ----------

__device__ __forceinline__ unsigned short f2bf_rne(float f) {
    unsigned u = __builtin_bit_cast(unsigned, f);
    return (unsigned short)((u + 0x7fffu + ((u >> 16) & 1u)) >> 16);
}
__device__ __forceinline__ float bf2f(unsigned short h) {
    unsigned u = ((unsigned)h) << 16;
    return __builtin_bit_cast(float, u);
}

// async global->LDS, 16B per lane. LDS dst = wave-uniform base + lane*16.
__device__ __forceinline__ void gl_lds16(const void* g, void* l) {
    __builtin_amdgcn_global_load_lds(
        (const __attribute__((address_space(1))) unsigned int*)g,
        (__attribute__((address_space(3))) unsigned int*)l,
        16, 0, 0);
}

__device__ __forceinline__ int pack4(float a, float b, float c, float d, float inv) {
    int q0 = (int)rintf(a * inv) & 255;
    int q1 = (int)rintf(b * inv) & 255;
    int q2 = (int)rintf(c * inv) & 255;
    int q3 = (int)rintf(d * inv) & 255;
    return q0 | (q1 << 8) | (q2 << 16) | (q3 << 24);
}

// ---------- kernel 1: x fp32 -> i8 with per-row scale ----------
// One block per row (2048 floats). Thread t handles elems {4t..4t+3, 1024+4t..+3}.
__global__ __launch_bounds__(256) void quantize_x_kernel(
        const float4* __restrict__ x4, int* __restrict__ xq,
        float* __restrict__ scales) {
    __shared__ float wmax[4];
    const int row = blockIdx.x;
    const int t = threadIdx.x;
    const float4* xr = x4 + (size_t)row * 512;
    float4 a = xr[t];          // 16B coalesced
    float4 b = xr[t + 256];
    float m = fmaxf(fmaxf(fabsf(a.x), fabsf(a.y)), fmaxf(fabsf(a.z), fabsf(a.w)));
    m = fmaxf(m, fmaxf(fmaxf(fabsf(b.x), fabsf(b.y)), fmaxf(fabsf(b.z), fabsf(b.w))));
#pragma unroll
    for (int off = 32; off >= 1; off >>= 1) m = fmaxf(m, __shfl_xor(m, off));
    if ((t & 63) == 0) wmax[t >> 6] = m;
    __syncthreads();
    m = fmaxf(fmaxf(wmax[0], wmax[1]), fmaxf(wmax[2], wmax[3]));
    m = fmaxf(m, 1e-20f);                 // guard all-zero row
    const float inv = 127.0f / m;
    if (t == 0) scales[row] = m * (1.0f / 127.0f);
    int* xo = xq + (size_t)row * 512;
    xo[t]       = pack4(a.x, a.y, a.z, a.w, inv);   // 4B coalesced
    xo[t + 256] = pack4(b.x, b.y, b.z, b.w, inv);
}

// ---------- kernel 2: w fp32 -> sign i8 (+1/-1); also zero stat accums ----------
__global__ __launch_bounds__(256) void convert_w_kernel(
        const float4* __restrict__ w, int* __restrict__ wq,
        float4* __restrict__ stats /* colsum[2048]+colsumsq[2048] */) {
    int id = blockIdx.x * 256 + threadIdx.x;       // exact: 4096 blocks
    if (id < 1024) stats[id] = make_float4(0.f, 0.f, 0.f, 0.f);
    float4 a = w[id];
    // w >= 0 -> +1, w < 0 -> -1 (byte 0xFF). (-0.0 >= 0 -> +1, matches ref)
    int b0 = (a.x < 0.f) ? 0xFF : 0x01;
    int b1 = (a.y < 0.f) ? 0xFF : 0x01;
    int b2 = (a.z < 0.f) ? 0xFF : 0x01;
    int b3 = (a.w < 0.f) ? 0xFF : 0x01;
    wq[id] = b0 | (b1 << 8) | (b2 << 16) | (b3 << 24);
}

// ---------- kernel 3: i8 GEMM (NT) + column sum/sumsq epilogue ----------
// A: [B_DIM, IN_DIM] i8; Bw: [OUT_DIM, IN_DIM] i8 (+1/-1). D = i32 exact dot;
// Y[m][n] = scales[m] * D[m][n], stored bf16. Stats accumulated fp32 from the
// same scaled values.
// 128x128 tile, BK=64 (64 B/row), 256 threads = 4 waves 2x2, each 4x4 of
// 16x16x64 i8 MFMA.
__global__ __launch_bounds__(256, 2) void gemm_bn_kernel(
        const char* __restrict__ A, const char* __restrict__ Bw,
        const float* __restrict__ scales,
        unsigned short* __restrict__ Yb,
        float* __restrict__ colsum, float* __restrict__ colsumsq) {
    __shared__ char sA[128 * 64];   // row-major [row][k], 64B rows
    __shared__ char sB[128 * 64];

    const int tid  = threadIdx.x;
    const int wave = tid >> 6;
    const int lane = tid & 63;
    const int wm = wave >> 1;         // wave row (0..1) -> 64 rows of M
    const int wn = wave & 1;          // wave col (0..1) -> 64 cols of N
    const int lr = lane & 15;         // row/col within 16
    const int lq = lane >> 4;         // quad 0..3

    // XCD swizzle: blockIdx%8 round-robins across XCDs; remap so each XCD gets
    // contiguous logical tiles (16 full bm-rows) -> A-tile L2 locality.
    const int b  = blockIdx.x;                 // 0..2047
    const int lb = (b & 7) * 256 + (b >> 3);   // bijection on [0,2048)
    const int bm = (lb >> 4) * 128;            // 128 M tiles
    const int bn = (lb & 15) * 128;            // 16 N tiles

    // staging: each wave fills 2 chunks of 16 rows (16 rows x 64 B = 1024 B)
    const int srow = lane >> 2;                // 0..15
    const int scol = (lane & 3) * 16;          // 0,16,32,48
    const int chunk0 = wave * 2;
    const char* ag0 = A  + (size_t)(bm + chunk0 * 16 + srow) * IN_DIM + scol;
    const char* ag1 = ag0 + 16 * IN_DIM;
    const char* bg0 = Bw + (size_t)(bn + chunk0 * 16 + srow) * IN_DIM + scol;
    const char* bg1 = bg0 + 16 * IN_DIM;
    char* la0 = sA + chunk0 * 1024;
    char* la1 = sA + (chunk0 + 1) * 1024;
    char* lb0 = sB + chunk0 * 1024;
    char* lb1 = sB + (chunk0 + 1) * 1024;

    // fragment LDS offsets: lane holds row (tile16*16 + lr), k = lq*16..+15
    const int aoff = (wm * 64 + lr) * 64 + lq * 16;
    const int boff = (wn * 64 + lr) * 64 + lq * 16;

    i32x4 acc[4][4];
#pragma unroll
    for (int i = 0; i < 4; ++i)
#pragma unroll
        for (int j = 0; j < 4; ++j) {
            i32x4 z = {0, 0, 0, 0};
            acc[i][j] = z;
        }

    for (int k0 = 0; k0 < IN_DIM; k0 += 64) {
        __syncthreads();                       // previous tile's ds_reads done
        gl_lds16(ag0 + k0, la0);
        gl_lds16(ag1 + k0, la1);
        gl_lds16(bg0 + k0, lb0);
        gl_lds16(bg1 + k0, lb1);
        __syncthreads();                       // staging complete

        i32x4 av[4], bv[4];
#pragma unroll
        for (int i = 0; i < 4; ++i)
            av[i] = *(const i32x4*)(sA + aoff + i * 1024);
#pragma unroll
        for (int j = 0; j < 4; ++j)
            bv[j] = *(const i32x4*)(sB + boff + j * 1024);
#pragma unroll
        for (int i = 0; i < 4; ++i)
#pragma unroll
            for (int j = 0; j < 4; ++j)
                acc[i][j] = __builtin_amdgcn_mfma_i32_16x16x64_i8(
                    av[i], bv[j], acc[i][j], 0, 0, 0);
    }

    // epilogue: y = scales[m] * acc (C/D layout: col = lr, row = lq*4 + r)
    float colS[4], colQ[4];
#pragma unroll
    for (int j = 0; j < 4; ++j) { colS[j] = 0.f; colQ[j] = 0.f; }

#pragma unroll
    for (int i = 0; i < 4; ++i) {
        const int row0 = bm + wm * 64 + i * 16 + lq * 4;
        float sc[4];
#pragma unroll
        for (int r = 0; r < 4; ++r) sc[r] = scales[row0 + r];
#pragma unroll
        for (int r = 0; r < 4; ++r) {
            size_t base = (size_t)(row0 + r) * OUT_DIM + bn + wn * 64 + lr;
#pragma unroll
            for (int j = 0; j < 4; ++j) {
                float v = (float)acc[i][j][r] * sc[r];
                Yb[base + j * 16] = f2bf_rne(v);
                colS[j] += v;
                colQ[j] += v * v;
            }
        }
    }

    // per-column partial sum / sumsq -> atomics (combine 4 quads = 4 row groups)
#pragma unroll
    for (int j = 0; j < 4; ++j) {
        float s = colS[j], q = colQ[j];
        s += __shfl_xor(s, 16); s += __shfl_xor(s, 32);
        q += __shfl_xor(q, 16); q += __shfl_xor(q, 32);
        if (lq == 0) {
            int col = bn + wn * 64 + j * 16 + lr;
            atomicAdd(&colsum[col], s);
            atomicAdd(&colsumsq[col], q);
        }
    }
}

// ---------- kernel 4: finalize BN params ----------
__global__ __launch_bounds__(256) void finalize_kernel(
        const float* __restrict__ colsum, const float* __restrict__ colsumsq,
        const float* __restrict__ gamma, const float* __restrict__ beta,
        float* __restrict__ scale, float* __restrict__ bias) {
    int n = blockIdx.x * 256 + threadIdx.x;
    if (n < OUT_DIM) {
        const float inv = 1.f / (float)B_DIM;
        float mean = colsum[n] * inv;
        float var  = colsumsq[n] * inv - mean * mean;
        float sc   = gamma[n] * rsqrtf(var + BN_EPS);
        scale[n] = sc;
        bias[n]  = beta[n] - mean * sc;
    }
}

// ---------- kernel 5: bf16 Y -> affine+ReLU -> fp32 out. 4 elems/thread ----------
__global__ __launch_bounds__(256) void bn_relu_bf16_kernel(
        const u16x4* __restrict__ yb, float4* __restrict__ out,
        const float4* __restrict__ scale4, const float4* __restrict__ bias4) {
    int id = blockIdx.x * 256 + threadIdx.x;   // exact: 32768 blocks
    int c4 = id & (OUT_DIM / 4 - 1);           // column group (2048%4==0)
    u16x4 h = yb[id];                          // 8B coalesced read
    float4 s = scale4[c4];
    float4 b = bias4[c4];
    float4 v;
    v.x = fmaxf(fmaf(bf2f(h[0]), s.x, b.x), 0.f);
    v.y = fmaxf(fmaf(bf2f(h[1]), s.y, b.y), 0.f);
    v.z = fmaxf(fmaf(bf2f(h[2]), s.z, b.z), 0.f);
    v.w = fmaxf(fmaf(bf2f(h[3]), s.w, b.w), 0.f);
    out[id] = v;                               // 16B coalesced write
}

// ---------- launch ----------
extern "C" void kernel_launch(void* const* d_in, const int* in_sizes, int n_in,
                              void* d_out, int out_size, void* d_ws, size_t ws_size,
                              hipStream_t stream) {
    const float* x     = (const float*)d_in[0];   // [16384, 2048]
    const float* w     = (const float*)d_in[1];   // [2048, 2048]
    const float* gamma = (const float*)d_in[2];   // [2048]
    const float* beta  = (const float*)d_in[3];   // [2048]
    float* out = (float*)d_out;                   // [16384, 2048]

    char* ws = (char*)d_ws;
    // ws layout: xq 32MB | wq 4MB | yb 64MB | stats 32KB | scales 64KB
    const size_t XQ_OFF = 0;
    const size_t WQ_OFF = XQ_OFF + (size_t)B_DIM * IN_DIM;          // 33,554,432
    const size_t YB_OFF = WQ_OFF + (size_t)OUT_DIM * IN_DIM;        // 37,748,736
    const size_t ST_OFF = YB_OFF + (size_t)B_DIM * OUT_DIM * 2;     // 104,857,600
    const size_t SC_OFF = ST_OFF + 8192 * 4;                        // 104,890,368

    char* xq = ws + XQ_OFF;
    char* wq = ws + WQ_OFF;
    unsigned short* yb = (unsigned short*)(ws + YB_OFF);
    float* colsum   = (float*)(ws + ST_OFF);
    float* colsumsq = colsum + 2048;
    float* scale    = colsum + 4096;
    float* bias     = colsum + 6144;
    float* scales   = (float*)(ws + SC_OFF);      // per-row x scales [16384]

    quantize_x_kernel<<<B_DIM, 256, 0, stream>>>(
        (const float4*)x, (int*)xq, scales);
    convert_w_kernel<<<4096, 256, 0, stream>>>(
        (const float4*)w, (int*)wq, (float4*)colsum);
    gemm_bn_kernel<<<2048, 256, 0, stream>>>(
        xq, wq, scales, yb, colsum, colsumsq);
    finalize_kernel<<<8, 256, 0, stream>>>(
        colsum, colsumsq, gamma, beta, scale, bias);
    bn_relu_bf16_kernel<<<32768, 256, 0, stream>>>(
        (const u16x4*)yb, (float4*)out, (const float4*)scale,
        (const float4*)bias);
}

// Round 4
// 328.230 us; speedup vs baseline: 1.2970x; 1.0439x over previous
//
#include <hip/hip_runtime.h>
#include <stdint.h>

// Problem constants (from reference setup_inputs)
#define B_DIM   16384
#define IN_DIM  2048
#define OUT_DIM 2048
#define BN_EPS  1e-5f

typedef int    i32x4 __attribute__((ext_vector_type(4)));
typedef unsigned short u16x4 __attribute__((ext_vector_type(4)));

// ---------- helpers ----------

__device__ __forceinline__ unsigned short f2bf_rne(float f) {
    unsigned u = __builtin_bit_cast(unsigned, f);
    return (unsigned short)((u + 0x7fffu + ((u >> 16) & 1u)) >> 16);
}
__device__ __forceinline__ float bf2f(unsigned short h) {
    unsigned u = ((unsigned)h) << 16;
    return __builtin_bit_cast(float, u);
}

// async global->LDS, 16B per lane. LDS dst = wave-uniform base + lane*16.
__device__ __forceinline__ void gl_lds16(const void* g, void* l) {
    __builtin_amdgcn_global_load_lds(
        (const __attribute__((address_space(1))) unsigned int*)g,
        (__attribute__((address_space(3))) unsigned int*)l,
        16, 0, 0);
}

__device__ __forceinline__ int pack4(float a, float b, float c, float d, float inv) {
    int q0 = (int)rintf(a * inv) & 255;
    int q1 = (int)rintf(b * inv) & 255;
    int q2 = (int)rintf(c * inv) & 255;
    int q3 = (int)rintf(d * inv) & 255;
    return q0 | (q1 << 8) | (q2 << 16) | (q3 << 24);
}

// ---------- kernel 1: x fp32 -> i8 with per-row scale ----------
// One block per row (2048 floats). Thread t handles elems {4t..4t+3, 1024+4t..+3}.
__global__ __launch_bounds__(256) void quantize_x_kernel(
        const float4* __restrict__ x4, int* __restrict__ xq,
        float* __restrict__ scales) {
    __shared__ float wmax[4];
    const int row = blockIdx.x;
    const int t = threadIdx.x;
    const float4* xr = x4 + (size_t)row * 512;
    float4 a = xr[t];          // 16B coalesced
    float4 b = xr[t + 256];
    float m = fmaxf(fmaxf(fabsf(a.x), fabsf(a.y)), fmaxf(fabsf(a.z), fabsf(a.w)));
    m = fmaxf(m, fmaxf(fmaxf(fabsf(b.x), fabsf(b.y)), fmaxf(fabsf(b.z), fabsf(b.w))));
#pragma unroll
    for (int off = 32; off >= 1; off >>= 1) m = fmaxf(m, __shfl_xor(m, off));
    if ((t & 63) == 0) wmax[t >> 6] = m;
    __syncthreads();
    m = fmaxf(fmaxf(wmax[0], wmax[1]), fmaxf(wmax[2], wmax[3]));
    m = fmaxf(m, 1e-20f);                 // guard all-zero row
    const float inv = 127.0f / m;
    if (t == 0) scales[row] = m * (1.0f / 127.0f);
    int* xo = xq + (size_t)row * 512;
    xo[t]       = pack4(a.x, a.y, a.z, a.w, inv);   // 4B coalesced
    xo[t + 256] = pack4(b.x, b.y, b.z, b.w, inv);
}

// ---------- kernel 2: w fp32 -> sign i8 (+1/-1); also zero stat accums ----------
__global__ __launch_bounds__(256) void convert_w_kernel(
        const float4* __restrict__ w, int* __restrict__ wq,
        float4* __restrict__ stats /* colsum[2048]+colsumsq[2048] */) {
    int id = blockIdx.x * 256 + threadIdx.x;       // exact: 4096 blocks
    if (id < 1024) stats[id] = make_float4(0.f, 0.f, 0.f, 0.f);
    float4 a = w[id];
    // w >= 0 -> +1, w < 0 -> -1 (byte 0xFF). (-0.0 >= 0 -> +1, matches ref)
    int b0 = (a.x < 0.f) ? 0xFF : 0x01;
    int b1 = (a.y < 0.f) ? 0xFF : 0x01;
    int b2 = (a.z < 0.f) ? 0xFF : 0x01;
    int b3 = (a.w < 0.f) ? 0xFF : 0x01;
    wq[id] = b0 | (b1 << 8) | (b2 << 16) | (b3 << 24);
}

// ---------- kernel 3: i8 GEMM (NT) + column sum/sumsq epilogue ----------
// A: [B_DIM, IN_DIM] i8; Bw: [OUT_DIM, IN_DIM] i8 (+1/-1). D = i32 exact dot;
// Y[m][n] = scales[m] * D[m][n], stored bf16. Stats accumulated fp32 from the
// same scaled values.
// 128x128 tile, BK=128 bytes (16 K-iters -> half the barrier drains of BK=64).
// LDS: two k-half slabs, each the proven [128 rows x 64 B] geometry.
// 256 threads = 4 waves 2x2; per k-half each wave does 4x4 of 16x16x64 MFMA.
__global__ __launch_bounds__(256, 2) void gemm_bn_kernel(
        const char* __restrict__ A, const char* __restrict__ Bw,
        const float* __restrict__ scales,
        unsigned short* __restrict__ Yb,
        float* __restrict__ colsum, float* __restrict__ colsumsq) {
    __shared__ char sA[2 * 128 * 64];   // [kh][row][64B]
    __shared__ char sB[2 * 128 * 64];

    const int tid  = threadIdx.x;
    const int wave = tid >> 6;
    const int lane = tid & 63;
    const int wm = wave >> 1;         // wave row (0..1) -> 64 rows of M
    const int wn = wave & 1;          // wave col (0..1) -> 64 cols of N
    const int lr = lane & 15;         // row/col within 16
    const int lq = lane >> 4;         // quad 0..3

    // XCD swizzle: blockIdx%8 round-robins across XCDs; remap so each XCD gets
    // contiguous logical tiles (16 full bm-rows) -> A-tile L2 locality.
    const int b  = blockIdx.x;                 // 0..2047
    const int lb = (b & 7) * 256 + (b >> 3);   // bijection on [0,2048)
    const int bm = (lb >> 4) * 128;            // 128 M tiles
    const int bn = (lb & 15) * 128;            // 16 N tiles

    // staging: 32 chunks/iter (A:16, B:16), 8 per wave. Chunk = 16 rows x 16B
    // of one k-half slab (1024 B, lane-contiguous). Chunk g of this wave:
    //   g' = wave*8+q; g'<16 -> A else B; slab=(g'>>3)&1; c=g'&7.
    const int srow = lane >> 2;                // 0..15
    const int scol = (lane & 3) * 16;          // 0,16,32,48
    const char* gp[8];
    char* lp[8];
#pragma unroll
    for (int q = 0; q < 8; ++q) {
        int g    = wave * 8 + q;
        int isB  = g >> 4;
        int slab = (g >> 3) & 1;
        int c    = g & 7;
        const char* basep = isB ? Bw : A;
        int tileoff       = isB ? bn : bm;
        gp[q] = basep + (size_t)(tileoff + c * 16 + srow) * IN_DIM
                      + slab * 64 + scol;
        char* sbase = isB ? sB : sA;
        lp[q] = sbase + slab * 8192 + c * 1024 + lane * 16;
    }

    // fragment LDS offsets within a slab: lane holds row (i*16 + lr),
    // k-bytes lq*16..+15; row stride 64 B (conflict-free, proven geometry).
    const int aoff = (wm * 64 + lr) * 64 + lq * 16;
    const int boff = (wn * 64 + lr) * 64 + lq * 16;

    i32x4 acc[4][4];
#pragma unroll
    for (int i = 0; i < 4; ++i)
#pragma unroll
        for (int j = 0; j < 4; ++j) {
            i32x4 z = {0, 0, 0, 0};
            acc[i][j] = z;
        }

    for (int k0 = 0; k0 < IN_DIM; k0 += 128) {
        __syncthreads();                       // previous iter's ds_reads done
#pragma unroll
        for (int q = 0; q < 8; ++q)
            gl_lds16(gp[q] + k0, lp[q]);
        __syncthreads();                       // staging complete

#pragma unroll
        for (int kh = 0; kh < 2; ++kh) {
            const char* aB = sA + kh * 8192 + aoff;
            const char* bB = sB + kh * 8192 + boff;
            i32x4 av[4], bv[4];
#pragma unroll
            for (int i = 0; i < 4; ++i)
                av[i] = *(const i32x4*)(aB + i * 1024);
#pragma unroll
            for (int j = 0; j < 4; ++j)
                bv[j] = *(const i32x4*)(bB + j * 1024);
#pragma unroll
            for (int i = 0; i < 4; ++i)
#pragma unroll
                for (int j = 0; j < 4; ++j)
                    acc[i][j] = __builtin_amdgcn_mfma_i32_16x16x64_i8(
                        av[i], bv[j], acc[i][j], 0, 0, 0);
        }
    }

    // epilogue: y = scales[m] * acc (C/D layout: col = lr, row = lq*4 + r)
    float colS[4], colQ[4];
#pragma unroll
    for (int j = 0; j < 4; ++j) { colS[j] = 0.f; colQ[j] = 0.f; }

#pragma unroll
    for (int i = 0; i < 4; ++i) {
        const int row0 = bm + wm * 64 + i * 16 + lq * 4;
        float sc[4];
#pragma unroll
        for (int r = 0; r < 4; ++r) sc[r] = scales[row0 + r];
#pragma unroll
        for (int r = 0; r < 4; ++r) {
            size_t base = (size_t)(row0 + r) * OUT_DIM + bn + wn * 64 + lr;
#pragma unroll
            for (int j = 0; j < 4; ++j) {
                float v = (float)acc[i][j][r] * sc[r];
                Yb[base + j * 16] = f2bf_rne(v);
                colS[j] += v;
                colQ[j] += v * v;
            }
        }
    }

    // per-column partial sum / sumsq -> atomics (combine 4 quads = 4 row groups)
#pragma unroll
    for (int j = 0; j < 4; ++j) {
        float s = colS[j], q = colQ[j];
        s += __shfl_xor(s, 16); s += __shfl_xor(s, 32);
        q += __shfl_xor(q, 16); q += __shfl_xor(q, 32);
        if (lq == 0) {
            int col = bn + wn * 64 + j * 16 + lr;
            atomicAdd(&colsum[col], s);
            atomicAdd(&colsumsq[col], q);
        }
    }
}

// ---------- kernel 4: finalize BN params ----------
__global__ __launch_bounds__(256) void finalize_kernel(
        const float* __restrict__ colsum, const float* __restrict__ colsumsq,
        const float* __restrict__ gamma, const float* __restrict__ beta,
        float* __restrict__ scale, float* __restrict__ bias) {
    int n = blockIdx.x * 256 + threadIdx.x;
    if (n < OUT_DIM) {
        const float inv = 1.f / (float)B_DIM;
        float mean = colsum[n] * inv;
        float var  = colsumsq[n] * inv - mean * mean;
        float sc   = gamma[n] * rsqrtf(var + BN_EPS);
        scale[n] = sc;
        bias[n]  = beta[n] - mean * sc;
    }
}

// ---------- kernel 5: bf16 Y -> affine+ReLU -> fp32 out. 8 elems/thread ----------
__global__ __launch_bounds__(256) void bn_relu_bf16_kernel(
        const u16x4* __restrict__ yb, float4* __restrict__ out,
        const float4* __restrict__ scale4, const float4* __restrict__ bias4) {
    int base = blockIdx.x * 512 + threadIdx.x;   // block covers 512 f4-groups
#pragma unroll
    for (int p = 0; p < 2; ++p) {
        int id = base + p * 256;                 // coalesced both passes
        int c4 = id & (OUT_DIM / 4 - 1);         // column group (2048%4==0)
        u16x4 h = yb[id];                        // 8B coalesced read
        float4 s = scale4[c4];
        float4 bb = bias4[c4];
        float4 v;
        v.x = fmaxf(fmaf(bf2f(h[0]), s.x, bb.x), 0.f);
        v.y = fmaxf(fmaf(bf2f(h[1]), s.y, bb.y), 0.f);
        v.z = fmaxf(fmaf(bf2f(h[2]), s.z, bb.z), 0.f);
        v.w = fmaxf(fmaf(bf2f(h[3]), s.w, bb.w), 0.f);
        out[id] = v;                             // 16B coalesced write
    }
}

// ---------- launch ----------
extern "C" void kernel_launch(void* const* d_in, const int* in_sizes, int n_in,
                              void* d_out, int out_size, void* d_ws, size_t ws_size,
                              hipStream_t stream) {
    const float* x     = (const float*)d_in[0];   // [16384, 2048]
    const float* w     = (const float*)d_in[1];   // [2048, 2048]
    const float* gamma = (const float*)d_in[2];   // [2048]
    const float* beta  = (const float*)d_in[3];   // [2048]
    float* out = (float*)d_out;                   // [16384, 2048]

    char* ws = (char*)d_ws;
    // ws layout: xq 32MB | wq 4MB | yb 64MB | stats 32KB | scales 64KB
    const size_t XQ_OFF = 0;
    const size_t WQ_OFF = XQ_OFF + (size_t)B_DIM * IN_DIM;          // 33,554,432
    const size_t YB_OFF = WQ_OFF + (size_t)OUT_DIM * IN_DIM;        // 37,748,736
    const size_t ST_OFF = YB_OFF + (size_t)B_DIM * OUT_DIM * 2;     // 104,857,600
    const size_t SC_OFF = ST_OFF + 8192 * 4;                        // 104,890,368

    char* xq = ws + XQ_OFF;
    char* wq = ws + WQ_OFF;
    unsigned short* yb = (unsigned short*)(ws + YB_OFF);
    float* colsum   = (float*)(ws + ST_OFF);
    float* colsumsq = colsum + 2048;
    float* scale    = colsum + 4096;
    float* bias     = colsum + 6144;
    float* scales   = (float*)(ws + SC_OFF);      // per-row x scales [16384]

    quantize_x_kernel<<<B_DIM, 256, 0, stream>>>(
        (const float4*)x, (int*)xq, scales);
    convert_w_kernel<<<4096, 256, 0, stream>>>(
        (const float4*)w, (int*)wq, (float4*)colsum);
    gemm_bn_kernel<<<2048, 256, 0, stream>>>(
        xq, wq, scales, yb, colsum, colsumsq);
    finalize_kernel<<<8, 256, 0, stream>>>(
        colsum, colsumsq, gamma, beta, scale, bias);
    bn_relu_bf16_kernel<<<16384, 256, 0, stream>>>(
        (const u16x4*)yb, (float4*)out, (const float4*)scale,
        (const float4*)bias);
}